// Round 5
// baseline (494.876 us; speedup 1.0000x reference)
//
#include <hip/hip_runtime.h>
#include <stdint.h>

#define NW 28
#define IMG 224
#define XD_TOTAL 1822272
#define POOL_ELEMS 26615808   /* 16*114*114*128 */
#define OUT_ELEMS 25690112    /* 16*128*112*112 */

/* workspace byte offsets (unchanged from round-1 passing layout) */
#define XD_OFF_B    0
#define POOL_OFF_B  3644928
#define W1P_OFF_B   56876544
#define W2T_OFF_B   56925696
#define STATS_OFF_B 57220608
/* tab lives in d_out tail: f ends at byte 93,667,328 of 102,760,448 */
#define TAB_OUT_OFF_B 93667328

typedef __attribute__((ext_vector_type(8))) short short8;
typedef __attribute__((ext_vector_type(4))) float f32x4;

/* w: t, l, h, w, sh, sw, xd_off, f_off, tile_start, tiles_per_b */
#define WIN_TABLE(W) \
  W(  0,  0, 16,208, 14,110,       0,        0,    0, 7) \
  W( 16,  0,208, 16,110, 14,   73920,  1703936,  112, 7) \
  W(208, 16, 16,208, 14,110,  147840,  3407872,  224, 7) \
  W(  0,208,208, 16,110, 14,  221760,  5111808,  336, 7) \
  W( 16, 16, 16,176, 15,102,  295680,  6815744,  448, 7) \
  W( 32, 16,176, 16,102, 15,  369120,  8585216,  560, 7) \
  W(192, 32, 16,176, 15,102,  442560, 10354688,  672, 7) \
  W( 16,192,176, 16,102, 15,  516000, 12124160,  784, 7) \
  W( 32, 32, 16,144, 16, 93,  589440, 13893632,  896, 7) \
  W( 48, 32,144, 16, 93, 16,  660864, 15675392, 1008, 7) \
  W(176, 48, 16,144, 16, 93,  732288, 17457152, 1120, 7) \
  W( 32,176,144, 16, 93, 16,  803712, 19238912, 1232, 7) \
  W( 48, 48, 16,112, 18, 82,  875136, 21020672, 1344, 8) \
  W( 64, 48,112, 16, 82, 18,  945984, 22888448, 1472, 8) \
  W(160, 64, 16,112, 18, 82, 1016832, 24756224, 1600, 8) \
  W( 48,160,112, 16, 82, 18, 1087680, 26624000, 1728, 8) \
  W( 64, 64, 16, 80, 21, 69, 1158528, 28491776, 1856, 8) \
  W( 80, 64, 80, 16, 69, 21, 1228080, 30427136, 1984, 8) \
  W(144, 80, 16, 80, 21, 69, 1297632, 32362496, 2112, 8) \
  W( 64,144, 80, 16, 69, 21, 1367184, 34297856, 2240, 8) \
  W( 80, 80, 16, 48, 24, 51, 1436736, 36233216, 2368, 7) \
  W( 96, 80, 48, 16, 51, 24, 1495488, 37892096, 2480, 7) \
  W(128, 96, 16, 48, 24, 51, 1554240, 39550976, 2592, 7) \
  W( 80,128, 48, 16, 51, 24, 1612992, 41209856, 2704, 7) \
  W( 96, 96, 16, 16, 28, 28, 1671744, 42868736, 2816, 4) \
  W(112, 96, 16, 16, 28, 28, 1709376, 43859968, 2880, 4) \
  W(112,112, 16, 16, 28, 28, 1747008, 44851200, 2944, 4) \
  W( 96,112, 16, 16, 28, 28, 1784640, 45842432, 3008, 4)

#define GT(t,l,h,ww,sh,sw,xdo,fo,ts,tpb) (t),
#define GL(t,l,h,ww,sh,sw,xdo,fo,ts,tpb) (l),
#define GH(t,l,h,ww,sh,sw,xdo,fo,ts,tpb) (h),
#define GW(t,l,h,ww,sh,sw,xdo,fo,ts,tpb) (ww),
#define GSH(t,l,h,ww,sh,sw,xdo,fo,ts,tpb) (sh),
#define GSW(t,l,h,ww,sh,sw,xdo,fo,ts,tpb) (sw),
#define GXO(t,l,h,ww,sh,sw,xdo,fo,ts,tpb) (xdo),
#define GFO(t,l,h,ww,sh,sw,xdo,fo,ts,tpb) (fo),
#define GTS(t,l,h,ww,sh,sw,xdo,fo,ts,tpb) (ts),
#define GTPB(t,l,h,ww,sh,sw,xdo,fo,ts,tpb) (tpb),
#define GXE(t,l,h,ww,sh,sw,xdo,fo,ts,tpb) ((xdo) + 48*(sh)*(sw)),
#define GTE(t,l,h,ww,sh,sw,xdo,fo,ts,tpb) ((ts) + 16*(tpb)),
#define GIH(t,l,h,ww,sh,sw,xdo,fo,ts,tpb) (1.0f/(float)(h)),
#define GIW(t,l,h,ww,sh,sw,xdo,fo,ts,tpb) (1.0f/(float)(ww)),
#define GIFW(t,l,h,ww,sh,sw,xdo,fo,ts,tpb) (1.0f/(float)((sw)-6)),
#define GRSY(t,l,h,ww,sh,sw,xdo,fo,ts,tpb) ((float)((h)+12)/(float)(sh)),
#define GRSX(t,l,h,ww,sh,sw,xdo,fo,ts,tpb) ((float)((ww)+12)/(float)(sw)),
#define GI3(t,l,h,ww,sh,sw,xdo,fo,ts,tpb) (1.0f/(float)(3*(sh)*(sw))),
#define GISS(t,l,h,ww,sh,sw,xdo,fo,ts,tpb) (1.0f/(float)((sh)*(sw))),
#define GISW(t,l,h,ww,sh,sw,xdo,fo,ts,tpb) (1.0f/(float)(sw)),

__constant__ int   W_T[NW]     = { WIN_TABLE(GT) };
__constant__ int   W_L[NW]     = { WIN_TABLE(GL) };
__constant__ int   W_H[NW]     = { WIN_TABLE(GH) };
__constant__ int   W_WW[NW]    = { WIN_TABLE(GW) };
__constant__ int   W_SH[NW]    = { WIN_TABLE(GSH) };
__constant__ int   W_SW[NW]    = { WIN_TABLE(GSW) };
__constant__ int   W_XDOFF[NW] = { WIN_TABLE(GXO) };
__constant__ int   W_FOFF[NW]  = { WIN_TABLE(GFO) };
__constant__ int   W_TSTART[NW]= { WIN_TABLE(GTS) };
__constant__ int   W_TPB[NW]   = { WIN_TABLE(GTPB) };
__constant__ int   W_XDEND[NW] = { WIN_TABLE(GXE) };
__constant__ int   W_TEND[NW]  = { WIN_TABLE(GTE) };
__constant__ float W_INVH[NW]  = { WIN_TABLE(GIH) };
__constant__ float W_INVW[NW]  = { WIN_TABLE(GIW) };
__constant__ float W_INVFW[NW] = { WIN_TABLE(GIFW) };
__constant__ float W_RSY[NW]   = { WIN_TABLE(GRSY) };
__constant__ float W_RSX[NW]   = { WIN_TABLE(GRSX) };
__constant__ float W_INV3[NW]  = { WIN_TABLE(GI3) };
__constant__ float W_INVSS[NW] = { WIN_TABLE(GISS) };
__constant__ float W_INVSW[NW] = { WIN_TABLE(GISW) };

__device__ __forceinline__ float bf2f(uint16_t h) {
  union { uint32_t u; float f; } v; v.u = ((uint32_t)h) << 16; return v.f;
}
__device__ __forceinline__ uint16_t f2bf(float x) {
  union { float f; uint32_t u; } v; v.f = x;
  uint32_t r = v.u + 0x7FFFu + ((v.u >> 16) & 1u);
  return (uint16_t)(r >> 16);
}

/* ---------------- prep: pack conv weights to bf16 ------------------------
   w1p: [cout][192] GEMM-B^T rows (k = (ch*7+ky)*8 + kx)
   w2f: MFMA fragment order: ((kk*2 + half)*4 + j)*512 + lane*8 + e
        cout = half*64 + j*16 + (lane&15); k = kk*32 + (lane>>4)*8 + e       */
__global__ void k_prep(const float* __restrict__ w1, const float* __restrict__ w2,
                       uint16_t* __restrict__ w1p, uint16_t* __restrict__ w2f) {
  int i = blockIdx.x * 256 + threadIdx.x;
  if (i < 128 * 192) {
    int cout = i / 192, k = i - cout * 192;
    int chunk = k >> 3, kx = k & 7;
    float v = 0.f;
    if (chunk < 21 && kx < 7) {
      int ch = chunk / 7, ky = chunk - ch * 7;
      v = w1[((cout * 3 + ch) * 7 + ky) * 7 + kx];
    }
    w1p[i] = f2bf(v);
  }
  int j2 = i - 128 * 192;
  if (j2 >= 0 && j2 < 128 * 1152) {
    int e    = j2 & 7;
    int lane = (j2 >> 3) & 63;
    int jj   = (j2 >> 9) & 3;
    int half = (j2 >> 11) & 1;
    int kk   = j2 >> 12;
    int cout = half * 64 + jj * 16 + (lane & 15);
    int k    = kk * 32 + ((lane >> 4) << 3) + e;
    int tap = k >> 7, ci = k & 127;
    int ty = tap / 3, tx = tap - ty * 3;
    w2f[j2] = f2bf(w2[((cout * 128 + ci) * 3 + ty) * 3 + tx]);
  }
}

/* ---------------- per-(y,x) tap lookup table for maxpool gather ----------- */
__global__ void k_tapoff(int2* __restrict__ tab) {
  int i = blockIdx.x * 256 + threadIdx.x;
  if (i >= IMG * IMG) return;
  int y = i / IMG, x = i - y * IMG;
  int dmin = min(min(y, 223 - y), min(x, 223 - x));
  int s = dmin >> 4; if (s > 6) s = 6;
  int b2 = (s << 4) + 16, cc = 208 - (s << 4);
  int side;
  if (y < b2) side = (x < cc) ? 0 : 3;
  else if (y >= cc) side = (x >= b2) ? 2 : 1;
  else side = (x < b2) ? 1 : 3;
  int w = (s << 2) + side;
  int fh = W_SH[w] - 6, fw = W_SW[w] - 6;
  int fy = (int)(((float)((y - W_T[w]) * fh) + 0.5f) * W_INVH[w]);
  int fx = (int)(((float)((x - W_L[w]) * fw) + 0.5f) * W_INVW[w]);
  tab[i] = make_int2(W_FOFF[w] + (fy * fw + fx) * 128, fh * fw * 128);
}

/* ---------------- resize: antialiased linear, per output element ---------- */
__global__ void k_resize(const float* __restrict__ inp, uint16_t* __restrict__ xd) {
  int idx = blockIdx.x * 256 + threadIdx.x;
  if (idx >= XD_TOTAL) return;
  int w = 0;
  while (w < NW - 1 && idx >= W_XDEND[w]) w++;
  int rem = idx - W_XDOFF[w];
  int sh = W_SH[w], sw = W_SW[w];
  int shsw = sh * sw;
  int b  = (int)(((float)rem + 0.5f) * W_INV3[w]);
  int r2 = rem - b * 3 * shsw;
  int ch = (int)(((float)r2 + 0.5f) * W_INVSS[w]);
  int r3 = r2 - ch * shsw;
  int oy = (int)(((float)r3 + 0.5f) * W_INVSW[w]);
  int ox = r3 - oy * sw;
  int t = W_T[w], l = W_L[w], h = W_H[w], ww = W_WW[w];
  int hiny = h + 12, hinx = ww + 12;
  float rsy = W_RSY[w], rsx = W_RSX[w];
  float iky = 1.0f / rsy, ikx = 1.0f / rsx;
  float sfy = ((float)oy + 0.5f) * rsy - 0.5f;
  float sfx = ((float)ox + 0.5f) * rsx - 0.5f;
  int y0 = (int)ceilf(sfy - rsy); if (y0 < 0) y0 = 0;
  int y1 = (int)floorf(sfy + rsy); if (y1 > hiny - 1) y1 = hiny - 1;
  int x0 = (int)ceilf(sfx - rsx); if (x0 < 0) x0 = 0;
  int x1 = (int)floorf(sfx + rsx); if (x1 > hinx - 1) x1 = hinx - 1;
  float wy[4], wx[4], sy = 0.f, sx = 0.f;
  #pragma unroll
  for (int k = 0; k < 4; k++) {
    int iy = y0 + k;
    float a = (iy <= y1) ? fmaxf(0.f, 1.f - fabsf((float)iy - sfy) * iky) : 0.f;
    wy[k] = a; sy += a;
    int ix = x0 + k;
    float a2 = (ix <= x1) ? fmaxf(0.f, 1.f - fabsf((float)ix - sfx) * ikx) : 0.f;
    wx[k] = a2; sx += a2;
  }
  const float* src = inp + (b * 3 + ch) * IMG * IMG;
  float accv = 0.f;
  #pragma unroll
  for (int ky = 0; ky < 4; ky++) {
    int gy = t + y0 + ky - 6;
    if (wy[ky] > 0.f && gy >= 0 && gy < IMG) {
      float rowa = 0.f;
      #pragma unroll
      for (int kx = 0; kx < 4; kx++) {
        int gx = l + x0 + kx - 6;
        if (wx[kx] > 0.f && gx >= 0 && gx < IMG)
          rowa += wx[kx] * src[gy * IMG + gx];
      }
      accv += wy[ky] * rowa;
    }
  }
  xd[idx] = f2bf(accv / (sy * sx));
}

/* ---------------- conv1 as implicit GEMM: M=window pixels, K=192, N=128 ---
   f output layout: NHWC  f[fo + (b*fhfw + pm)*128 + n]                      */
__global__ void k_conv1(const uint16_t* __restrict__ xd,
                        const uint16_t* __restrict__ w1p,
                        uint16_t* __restrict__ f) {
  __shared__ short8 As[512];
  __shared__ short8 Bs[512];
  int bid = blockIdx.x;
  int w = 0;
  while (w < NW - 1 && bid >= W_TEND[w]) w++;
  int rel = bid - W_TSTART[w];
  int tpb = W_TPB[w];
  int b  = rel / tpb;
  int mt = rel - b * tpb;
  int m0 = mt << 7;
  int sh = W_SH[w], sw = W_SW[w];
  int fh = sh - 6, fw = sw - 6;
  int fhfw = fh * fw;
  float invfw = W_INVFW[w];
  int xdo = W_XDOFF[w];
  int fo  = W_FOFF[w];
  int tid = threadIdx.x;
  int lane = tid & 63, wv = tid >> 6;
  int mn = tid & 127, q0 = tid >> 7;

  int pm0 = m0 + mn; if (pm0 > fhfw - 1) pm0 = fhfw - 1;
  int fy0 = (int)(((float)pm0 + 0.5f) * invfw);
  int fx0 = pm0 - fy0 * fw;
  const uint16_t* arow = xd + xdo + (b * 3) * sh * sw;
  const uint16_t* brow = w1p + mn * 192;

  f32x4 acc[4][4];
  #pragma unroll
  for (int i = 0; i < 4; i++)
    #pragma unroll
    for (int j = 0; j < 4; j++)
      acc[i][j] = (f32x4){0.f, 0.f, 0.f, 0.f};

  for (int kk = 0; kk < 6; kk++) {
    short8 av[2], bv[2];
    #pragma unroll
    for (int j = 0; j < 2; j++) {
      int q = (j << 1) | q0;
      int gc = (kk << 2) + q;
      const uint16_t* src;
      if (gc < 21) {
        int ch = gc / 7, ky = gc - ch * 7;
        src = arow + (ch * sh + fy0 + ky) * sw + fx0;
      } else {
        src = xd;  /* dummy; matching weights are zero */
      }
      short8 pk;
      pk[0]=(short)src[0]; pk[1]=(short)src[1]; pk[2]=(short)src[2]; pk[3]=(short)src[3];
      pk[4]=(short)src[4]; pk[5]=(short)src[5]; pk[6]=(short)src[6]; pk[7]=(short)src[7];
      av[j] = pk;
      bv[j] = *(const short8*)(brow + (kk << 5) + (q << 3));
    }
    __syncthreads();
    #pragma unroll
    for (int j = 0; j < 2; j++) {
      int ck = (j << 8) + tid;
      As[ck] = av[j];
      Bs[ck] = bv[j];
    }
    __syncthreads();
    int q = lane >> 4, ln = lane & 15;
    int wmB = (wv >> 1) << 6, wnB = (wv & 1) << 6;
    short8 af[4], bfr[4];
    #pragma unroll
    for (int i = 0; i < 4; i++) af[i]  = As[(q << 7) + wmB + (i << 4) + ln];
    #pragma unroll
    for (int j = 0; j < 4; j++) bfr[j] = Bs[(q << 7) + wnB + (j << 4) + ln];
    #pragma unroll
    for (int i = 0; i < 4; i++)
      #pragma unroll
      for (int j = 0; j < 4; j++)
        acc[i][j] = __builtin_amdgcn_mfma_f32_16x16x32_bf16(af[i], bfr[j], acc[i][j], 0, 0, 0);
  }

  int q = lane >> 4, ln = lane & 15;
  int wmB = (wv >> 1) << 6, wnB = (wv & 1) << 6;
  int base = fo + b * fhfw * 128;
  #pragma unroll
  for (int i = 0; i < 4; i++) {
    #pragma unroll
    for (int j = 0; j < 4; j++) {
      int n = wnB + (j << 4) + ln;
      int mrow = m0 + wmB + (i << 4) + (q << 2);
      #pragma unroll
      for (int r = 0; r < 4; r++) {
        int pm = mrow + r;
        if (pm < fhfw) f[base + pm * 128 + n] = f2bf(acc[i][j][r]);
      }
    }
  }
}

/* ---------------- BN1 stats over the virtual mosaic via multiplicities ----
   NHWC f: block = (w, b), 1024 threads: c = tid&127, e strided by 8        */
__global__ void k_stats1(const uint16_t* __restrict__ f, float* __restrict__ sums) {
  __shared__ float cwt[960];
  __shared__ float sS[128], sQ[128];
  int w = blockIdx.x;
  int b = blockIdx.y;
  int sh = W_SH[w], sw = W_SW[w];
  int fh = sh - 6, fw = sw - 6, fhfw = fh * fw;
  int h = W_H[w], ww = W_WW[w];
  int tid = threadIdx.x;
  if (tid < 128) { sS[tid] = 0.f; sQ[tid] = 0.f; }
  for (int e = tid; e < fhfw; e += 1024) {
    int fy = e / fw, fx = e - fy * fw;
    int cy = ((fy + 1) * h + fh - 1) / fh - (fy * h + fh - 1) / fh;
    int cx = ((fx + 1) * ww + fw - 1) / fw - (fx * ww + fw - 1) / fw;
    cwt[e] = (float)(cy * cx);
  }
  __syncthreads();
  int c = tid & 127, eh = tid >> 7;
  int base = W_FOFF[w] + b * fhfw * 128;
  float s = 0.f, q2 = 0.f;
  for (int e = eh; e < fhfw; e += 8) {
    float v = bf2f(f[base + e * 128 + c]);
    float cw = cwt[e];
    s += v * cw; q2 += v * v * cw;
  }
  atomicAdd(&sS[c], s);
  atomicAdd(&sQ[c], q2);
  __syncthreads();
  if (tid < 128) {
    atomicAdd(&sums[tid], sS[tid]);
    atomicAdd(&sums[128 + tid], sQ[tid]);
  }
}

__global__ void k_bnparam(const float* __restrict__ sums,
                          const float* __restrict__ gamma, const float* __restrict__ beta,
                          float n, float* __restrict__ scale, float* __restrict__ bias) {
  int c = threadIdx.x;
  float mean = sums[c] / n;
  float var = sums[128 + c] / n - mean * mean;
  var = fmaxf(var, 0.f);
  float sc = gamma[c] / sqrtf(var + 1e-5f);
  scale[c] = sc;
  bias[c] = beta[c] - mean * sc;
}

/* ---------------- BN1+ReLU+maxpool gather into padded NHWC bf16 -----------
   thread = 8 channels of one pooled pixel; 16 threads/pixel, 16 px/block    */
__global__ void k_maxpool(const uint16_t* __restrict__ f,
                          const float* __restrict__ scale, const float* __restrict__ bias,
                          const int2* __restrict__ tab,
                          uint16_t* __restrict__ pooled) {
  int tid = threadIdx.x;
  int g = blockIdx.x * 16 + (tid >> 4);   /* pooled pixel in [0, 16*114*114) */
  int c0 = (tid & 15) << 3;
  int xx = g % 114;
  int r  = g / 114;
  int yy = r % 114;
  int bb = r / 114;
  short8 outv = (short8){0,0,0,0,0,0,0,0};
  if (yy >= 1 && yy <= 112 && xx >= 1 && xx <= 112) {
    float m[8];
    #pragma unroll
    for (int k = 0; k < 8; k++) m[k] = -1e30f;
    int py = yy - 1, px = xx - 1;
    #pragma unroll
    for (int dy = 0; dy < 3; dy++) {
      int y = 2 * py - 1 + dy;
      if (y < 0) continue;
      #pragma unroll
      for (int dx = 0; dx < 3; dx++) {
        int x = 2 * px - 1 + dx;
        if (x < 0) continue;
        int2 t = tab[y * IMG + x];
        short8 v = *(const short8*)(f + t.x + bb * t.y + c0);
        #pragma unroll
        for (int k = 0; k < 8; k++) m[k] = fmaxf(m[k], bf2f((uint16_t)v[k]));
      }
    }
    f32x4 s0 = *(const f32x4*)(scale + c0);
    f32x4 s1 = *(const f32x4*)(scale + c0 + 4);
    f32x4 b0 = *(const f32x4*)(bias + c0);
    f32x4 b1 = *(const f32x4*)(bias + c0 + 4);
    #pragma unroll
    for (int k = 0; k < 4; k++) {
      outv[k]     = (short)f2bf(fmaxf(m[k]     * s0[k] + b0[k], 0.f));
      outv[k + 4] = (short)f2bf(fmaxf(m[k + 4] * s1[k] + b1[k], 0.f));
    }
  }
  *(short8*)(pooled + (size_t)g * 128 + c0) = outv;
}

/* ---------------- conv2: barrier-free implicit GEMM ----------------------
   A fragments loaded directly from NHWC pooled (16B aligned contiguous),
   B fragments from fragment-ordered w2f. No LDS staging, no __syncthreads
   in the K-loop. Fused BN2 partial stats in epilogue.                       */
__global__ void k_conv2(const uint16_t* __restrict__ pooled,
                        const uint16_t* __restrict__ w2f,
                        float* __restrict__ out, float* __restrict__ sums) {
  __shared__ float sS[128], sQ[128];
  int bid = blockIdx.x;
  int b = bid / 98;
  int m0 = bid << 7;
  int local0 = m0 - b * 12544;
  int tid = threadIdx.x;
  int lane = tid & 63, wv = tid >> 6;
  int q = lane >> 4, ln = lane & 15;
  int wmB = (wv >> 1) << 6;
  int half = wv & 1;
  int wnB = half << 6;
  if (tid < 128) { sS[tid] = 0.f; sQ[tid] = 0.f; }

  const uint16_t* ap = pooled + (size_t)b * 114 * 114 * 128;
  int rowoff[4];
  #pragma unroll
  for (int i = 0; i < 4; i++) {
    int pm = local0 + wmB + (i << 4) + ln;
    int yp = pm / 112, xp = pm - yp * 112;
    rowoff[i] = (yp * 114 + xp) * 128;
  }

  f32x4 acc[4][4];
  #pragma unroll
  for (int i = 0; i < 4; i++)
    #pragma unroll
    for (int j = 0; j < 4; j++)
      acc[i][j] = (f32x4){0.f, 0.f, 0.f, 0.f};

  const uint16_t* bbase = w2f + (half << 11) + (lane << 3);

  #pragma unroll
  for (int tap = 0; tap < 9; tap++) {
    const int ty = tap / 3, tx = tap - ty * 3;
    int tbase = (ty * 114 + tx) * 128 + (q << 3);
    #pragma unroll
    for (int cc = 0; cc < 4; cc++) {
      int kk = (tap << 2) + cc;
      int c0 = cc << 5;
      short8 af[4], bfr[4];
      #pragma unroll
      for (int i = 0; i < 4; i++)
        af[i] = *(const short8*)(ap + rowoff[i] + tbase + c0);
      #pragma unroll
      for (int j = 0; j < 4; j++)
        bfr[j] = *(const short8*)(bbase + (kk << 12) + (j << 9));
      #pragma unroll
      for (int i = 0; i < 4; i++)
        #pragma unroll
        for (int j = 0; j < 4; j++)
          acc[i][j] = __builtin_amdgcn_mfma_f32_16x16x32_bf16(af[i], bfr[j], acc[i][j], 0, 0, 0);
    }
  }

  #pragma unroll
  for (int i = 0; i < 4; i++) {
    #pragma unroll
    for (int j = 0; j < 4; j++) {
      int n = wnB + (j << 4) + ln;
      int prow = local0 + wmB + (i << 4) + (q << 2);
      float* dst = out + (size_t)(b * 128 + n) * 12544 + prow;
      *(f32x4*)dst = acc[i][j];
    }
  }
  __syncthreads();   /* make sS/sQ zero-init visible before atomics */
  #pragma unroll
  for (int j = 0; j < 4; j++) {
    int n = wnB + (j << 4) + ln;
    float s = 0.f, q2 = 0.f;
    #pragma unroll
    for (int i = 0; i < 4; i++)
      #pragma unroll
      for (int r = 0; r < 4; r++) {
        float v = acc[i][j][r];
        s += v; q2 += v * v;
      }
    atomicAdd(&sS[n], s);
    atomicAdd(&sQ[n], q2);
  }
  __syncthreads();
  if (tid < 128) {
    atomicAdd(&sums[tid], sS[tid]);
    atomicAdd(&sums[128 + tid], sQ[tid]);
  }
}

__global__ void k_final(f32x4* __restrict__ out,
                        const float* __restrict__ scale, const float* __restrict__ bias) {
  int i = blockIdx.x * 256 + threadIdx.x;
  int c = (i / 3136) & 127;   /* 12544 floats per channel = 3136 float4 */
  f32x4 v = out[i];
  float sc = scale[c], bi = bias[c];
  #pragma unroll
  for (int k = 0; k < 4; k++) v[k] = fmaxf(v[k] * sc + bi, 0.f);
  out[i] = v;
}

extern "C" void kernel_launch(void* const* d_in, const int* in_sizes, int n_in,
                              void* d_out, int out_size, void* d_ws, size_t ws_size,
                              hipStream_t stream) {
  (void)in_sizes; (void)n_in; (void)out_size; (void)ws_size;
  const float* inp = (const float*)d_in[0];
  const float* w1  = (const float*)d_in[1];
  const float* g1  = (const float*)d_in[2];
  const float* b1  = (const float*)d_in[3];
  const float* w2  = (const float*)d_in[4];
  const float* g2  = (const float*)d_in[5];
  const float* b2  = (const float*)d_in[6];
  float* out = (float*)d_out;
  char* ws = (char*)d_ws;
  uint16_t* xd     = (uint16_t*)(ws + XD_OFF_B);
  uint16_t* pooled = (uint16_t*)(ws + POOL_OFF_B);
  uint16_t* w1p    = (uint16_t*)(ws + W1P_OFF_B);
  uint16_t* w2f    = (uint16_t*)(ws + W2T_OFF_B);
  float* stats  = (float*)(ws + STATS_OFF_B);
  int2*  tab    = (int2*)((char*)d_out + TAB_OUT_OFF_B);  /* d_out tail; dead before conv2 writes */
  float* sums1  = stats;
  float* sums2  = stats + 256;
  float* scale1 = stats + 512;
  float* bias1  = stats + 640;
  float* scale2 = stats + 768;
  float* bias2  = stats + 896;
  uint16_t* f = (uint16_t*)d_out;   /* bf16 scratch inside d_out; dead before conv2 writes */

  hipMemsetAsync(stats, 0, 2048, stream);
  k_prep   <<<dim3(672),        dim3(256),  0, stream>>>(w1, w2, w1p, w2f);
  k_tapoff <<<dim3(196),        dim3(256),  0, stream>>>(tab);
  k_resize <<<dim3(7119),       dim3(256),  0, stream>>>(inp, xd);
  k_conv1  <<<dim3(3072),       dim3(256),  0, stream>>>(xd, w1p, f);
  k_stats1 <<<dim3(28, 16),     dim3(1024), 0, stream>>>(f, sums1);
  k_bnparam<<<dim3(1),          dim3(128),  0, stream>>>(sums1, g1, b1, 802816.0f, scale1, bias1);
  k_maxpool<<<dim3(12996),      dim3(256),  0, stream>>>(f, scale1, bias1, tab, pooled);
  k_conv2  <<<dim3(1568),       dim3(256),  0, stream>>>(pooled, w2f, out, sums2);
  k_bnparam<<<dim3(1),          dim3(128),  0, stream>>>(sums2, g2, b2, 200704.0f, scale2, bias2);
  k_final  <<<dim3(25088),      dim3(256),  0, stream>>>((f32x4*)out, scale2, bias2);
}

// Round 6
// 471.637 us; speedup vs baseline: 1.0493x; 1.0493x over previous
//
#include <hip/hip_runtime.h>
#include <stdint.h>

#define NW 28
#define IMG 224
#define XD_TOTAL 1822272
#define POOL_ELEMS 26615808   /* 16*114*114*128 */
#define OUT_ELEMS 25690112    /* 16*128*112*112 */

/* workspace byte offsets (unchanged from round-1 passing layout) */
#define XD_OFF_B    0
#define POOL_OFF_B  3644928
#define W1P_OFF_B   56876544
#define W2T_OFF_B   56925696
#define STATS_OFF_B 57220608
/* tab lives in d_out tail: f ends at byte 93,667,328 of 102,760,448 */
#define TAB_OUT_OFF_B 93667328

typedef __attribute__((ext_vector_type(8))) short short8;
typedef __attribute__((ext_vector_type(4))) float f32x4;

/* async global->LDS 16B: per-lane global addr, LDS dest = uniform base + lane*16 */
#define GLD16(gp, lp) __builtin_amdgcn_global_load_lds( \
    (const __attribute__((address_space(1))) void*)(gp), \
    (__attribute__((address_space(3))) void*)(lp), 16, 0, 0)

/* w: t, l, h, w, sh, sw, xd_off, f_off, tile_start, tiles_per_b */
#define WIN_TABLE(W) \
  W(  0,  0, 16,208, 14,110,       0,        0,    0, 7) \
  W( 16,  0,208, 16,110, 14,   73920,  1703936,  112, 7) \
  W(208, 16, 16,208, 14,110,  147840,  3407872,  224, 7) \
  W(  0,208,208, 16,110, 14,  221760,  5111808,  336, 7) \
  W( 16, 16, 16,176, 15,102,  295680,  6815744,  448, 7) \
  W( 32, 16,176, 16,102, 15,  369120,  8585216,  560, 7) \
  W(192, 32, 16,176, 15,102,  442560, 10354688,  672, 7) \
  W( 16,192,176, 16,102, 15,  516000, 12124160,  784, 7) \
  W( 32, 32, 16,144, 16, 93,  589440, 13893632,  896, 7) \
  W( 48, 32,144, 16, 93, 16,  660864, 15675392, 1008, 7) \
  W(176, 48, 16,144, 16, 93,  732288, 17457152, 1120, 7) \
  W( 32,176,144, 16, 93, 16,  803712, 19238912, 1232, 7) \
  W( 48, 48, 16,112, 18, 82,  875136, 21020672, 1344, 8) \
  W( 64, 48,112, 16, 82, 18,  945984, 22888448, 1472, 8) \
  W(160, 64, 16,112, 18, 82, 1016832, 24756224, 1600, 8) \
  W( 48,160,112, 16, 82, 18, 1087680, 26624000, 1728, 8) \
  W( 64, 64, 16, 80, 21, 69, 1158528, 28491776, 1856, 8) \
  W( 80, 64, 80, 16, 69, 21, 1228080, 30427136, 1984, 8) \
  W(144, 80, 16, 80, 21, 69, 1297632, 32362496, 2112, 8) \
  W( 64,144, 80, 16, 69, 21, 1367184, 34297856, 2240, 8) \
  W( 80, 80, 16, 48, 24, 51, 1436736, 36233216, 2368, 7) \
  W( 96, 80, 48, 16, 51, 24, 1495488, 37892096, 2480, 7) \
  W(128, 96, 16, 48, 24, 51, 1554240, 39550976, 2592, 7) \
  W( 80,128, 48, 16, 51, 24, 1612992, 41209856, 2704, 7) \
  W( 96, 96, 16, 16, 28, 28, 1671744, 42868736, 2816, 4) \
  W(112, 96, 16, 16, 28, 28, 1709376, 43859968, 2880, 4) \
  W(112,112, 16, 16, 28, 28, 1747008, 44851200, 2944, 4) \
  W( 96,112, 16, 16, 28, 28, 1784640, 45842432, 3008, 4)

#define GT(t,l,h,ww,sh,sw,xdo,fo,ts,tpb) (t),
#define GL(t,l,h,ww,sh,sw,xdo,fo,ts,tpb) (l),
#define GH(t,l,h,ww,sh,sw,xdo,fo,ts,tpb) (h),
#define GW(t,l,h,ww,sh,sw,xdo,fo,ts,tpb) (ww),
#define GSH(t,l,h,ww,sh,sw,xdo,fo,ts,tpb) (sh),
#define GSW(t,l,h,ww,sh,sw,xdo,fo,ts,tpb) (sw),
#define GXO(t,l,h,ww,sh,sw,xdo,fo,ts,tpb) (xdo),
#define GFO(t,l,h,ww,sh,sw,xdo,fo,ts,tpb) (fo),
#define GTS(t,l,h,ww,sh,sw,xdo,fo,ts,tpb) (ts),
#define GTPB(t,l,h,ww,sh,sw,xdo,fo,ts,tpb) (tpb),
#define GXE(t,l,h,ww,sh,sw,xdo,fo,ts,tpb) ((xdo) + 48*(sh)*(sw)),
#define GTE(t,l,h,ww,sh,sw,xdo,fo,ts,tpb) ((ts) + 16*(tpb)),
#define GIH(t,l,h,ww,sh,sw,xdo,fo,ts,tpb) (1.0f/(float)(h)),
#define GIW(t,l,h,ww,sh,sw,xdo,fo,ts,tpb) (1.0f/(float)(ww)),
#define GIFW(t,l,h,ww,sh,sw,xdo,fo,ts,tpb) (1.0f/(float)((sw)-6)),
#define GRSY(t,l,h,ww,sh,sw,xdo,fo,ts,tpb) ((float)((h)+12)/(float)(sh)),
#define GRSX(t,l,h,ww,sh,sw,xdo,fo,ts,tpb) ((float)((ww)+12)/(float)(sw)),
#define GI3(t,l,h,ww,sh,sw,xdo,fo,ts,tpb) (1.0f/(float)(3*(sh)*(sw))),
#define GISS(t,l,h,ww,sh,sw,xdo,fo,ts,tpb) (1.0f/(float)((sh)*(sw))),
#define GISW(t,l,h,ww,sh,sw,xdo,fo,ts,tpb) (1.0f/(float)(sw)),

__constant__ int   W_T[NW]     = { WIN_TABLE(GT) };
__constant__ int   W_L[NW]     = { WIN_TABLE(GL) };
__constant__ int   W_H[NW]     = { WIN_TABLE(GH) };
__constant__ int   W_WW[NW]    = { WIN_TABLE(GW) };
__constant__ int   W_SH[NW]    = { WIN_TABLE(GSH) };
__constant__ int   W_SW[NW]    = { WIN_TABLE(GSW) };
__constant__ int   W_XDOFF[NW] = { WIN_TABLE(GXO) };
__constant__ int   W_FOFF[NW]  = { WIN_TABLE(GFO) };
__constant__ int   W_TSTART[NW]= { WIN_TABLE(GTS) };
__constant__ int   W_TPB[NW]   = { WIN_TABLE(GTPB) };
__constant__ int   W_XDEND[NW] = { WIN_TABLE(GXE) };
__constant__ int   W_TEND[NW]  = { WIN_TABLE(GTE) };
__constant__ float W_INVH[NW]  = { WIN_TABLE(GIH) };
__constant__ float W_INVW[NW]  = { WIN_TABLE(GIW) };
__constant__ float W_INVFW[NW] = { WIN_TABLE(GIFW) };
__constant__ float W_RSY[NW]   = { WIN_TABLE(GRSY) };
__constant__ float W_RSX[NW]   = { WIN_TABLE(GRSX) };
__constant__ float W_INV3[NW]  = { WIN_TABLE(GI3) };
__constant__ float W_INVSS[NW] = { WIN_TABLE(GISS) };
__constant__ float W_INVSW[NW] = { WIN_TABLE(GISW) };

__device__ __forceinline__ float bf2f(uint16_t h) {
  union { uint32_t u; float f; } v; v.u = ((uint32_t)h) << 16; return v.f;
}
__device__ __forceinline__ uint16_t f2bf(float x) {
  union { float f; uint32_t u; } v; v.f = x;
  uint32_t r = v.u + 0x7FFFu + ((v.u >> 16) & 1u);
  return (uint16_t)(r >> 16);
}

/* ---------------- prep: pack conv weights to bf16, GEMM-B^T layouts ------- */
__global__ void k_prep(const float* __restrict__ w1, const float* __restrict__ w2,
                       uint16_t* __restrict__ w1p, uint16_t* __restrict__ w2t) {
  int i = blockIdx.x * 256 + threadIdx.x;
  if (i < 128 * 192) {            /* w1p[cout][192]: k = (ch*7+ky)*8 + kx, kx<7 real */
    int cout = i / 192, k = i - cout * 192;
    int chunk = k >> 3, kx = k & 7;
    float v = 0.f;
    if (chunk < 21 && kx < 7) {
      int ch = chunk / 7, ky = chunk - ch * 7;
      v = w1[((cout * 3 + ch) * 7 + ky) * 7 + kx];
    }
    w1p[i] = f2bf(v);
  }
  int j = i - 128 * 192;
  if (j >= 0 && j < 128 * 1152) { /* w2t[cout][1152]: k = tap*128 + cin */
    int cout = j / 1152, k = j - cout * 1152;
    int tap = k >> 7, ci = k & 127;
    int ty = tap / 3, tx = tap - ty * 3;
    w2t[j] = f2bf(w2[((cout * 128 + ci) * 3 + ty) * 3 + tx]);
  }
}

/* ---------------- per-(y,x) tap lookup table for maxpool gather ----------- */
__global__ void k_tapoff(int2* __restrict__ tab) {
  int i = blockIdx.x * 256 + threadIdx.x;
  if (i >= IMG * IMG) return;
  int y = i / IMG, x = i - y * IMG;
  int dmin = min(min(y, 223 - y), min(x, 223 - x));
  int s = dmin >> 4; if (s > 6) s = 6;
  int b2 = (s << 4) + 16, cc = 208 - (s << 4);
  int side;
  if (y < b2) side = (x < cc) ? 0 : 3;
  else if (y >= cc) side = (x >= b2) ? 2 : 1;
  else side = (x < b2) ? 1 : 3;
  int w = (s << 2) + side;
  int fh = W_SH[w] - 6, fw = W_SW[w] - 6;
  int fy = (int)(((float)((y - W_T[w]) * fh) + 0.5f) * W_INVH[w]);
  int fx = (int)(((float)((x - W_L[w]) * fw) + 0.5f) * W_INVW[w]);
  tab[i] = make_int2(W_FOFF[w] + (fy * fw + fx) * 128, fh * fw * 128);
}

/* ---------------- resize: antialiased linear, per output element ---------- */
__global__ void k_resize(const float* __restrict__ inp, uint16_t* __restrict__ xd) {
  int idx = blockIdx.x * 256 + threadIdx.x;
  if (idx >= XD_TOTAL) return;
  int w = 0;
  while (w < NW - 1 && idx >= W_XDEND[w]) w++;
  int rem = idx - W_XDOFF[w];
  int sh = W_SH[w], sw = W_SW[w];
  int shsw = sh * sw;
  int b  = (int)(((float)rem + 0.5f) * W_INV3[w]);
  int r2 = rem - b * 3 * shsw;
  int ch = (int)(((float)r2 + 0.5f) * W_INVSS[w]);
  int r3 = r2 - ch * shsw;
  int oy = (int)(((float)r3 + 0.5f) * W_INVSW[w]);
  int ox = r3 - oy * sw;
  int t = W_T[w], l = W_L[w], h = W_H[w], ww = W_WW[w];
  int hiny = h + 12, hinx = ww + 12;
  float rsy = W_RSY[w], rsx = W_RSX[w];
  float iky = 1.0f / rsy, ikx = 1.0f / rsx;
  float sfy = ((float)oy + 0.5f) * rsy - 0.5f;
  float sfx = ((float)ox + 0.5f) * rsx - 0.5f;
  int y0 = (int)ceilf(sfy - rsy); if (y0 < 0) y0 = 0;
  int y1 = (int)floorf(sfy + rsy); if (y1 > hiny - 1) y1 = hiny - 1;
  int x0 = (int)ceilf(sfx - rsx); if (x0 < 0) x0 = 0;
  int x1 = (int)floorf(sfx + rsx); if (x1 > hinx - 1) x1 = hinx - 1;
  float wy[4], wx[4], sy = 0.f, sx = 0.f;
  #pragma unroll
  for (int k = 0; k < 4; k++) {
    int iy = y0 + k;
    float a = (iy <= y1) ? fmaxf(0.f, 1.f - fabsf((float)iy - sfy) * iky) : 0.f;
    wy[k] = a; sy += a;
    int ix = x0 + k;
    float a2 = (ix <= x1) ? fmaxf(0.f, 1.f - fabsf((float)ix - sfx) * ikx) : 0.f;
    wx[k] = a2; sx += a2;
  }
  const float* src = inp + (b * 3 + ch) * IMG * IMG;
  float accv = 0.f;
  #pragma unroll
  for (int ky = 0; ky < 4; ky++) {
    int gy = t + y0 + ky - 6;
    if (wy[ky] > 0.f && gy >= 0 && gy < IMG) {
      float rowa = 0.f;
      #pragma unroll
      for (int kx = 0; kx < 4; kx++) {
        int gx = l + x0 + kx - 6;
        if (wx[kx] > 0.f && gx >= 0 && gx < IMG)
          rowa += wx[kx] * src[gy * IMG + gx];
      }
      accv += wy[ky] * rowa;
    }
  }
  xd[idx] = f2bf(accv / (sy * sx));
}

/* ---------------- conv1 as implicit GEMM: M=window pixels, K=192, N=128 ---
   f output layout: NHWC  f[fo + (b*fhfw + pm)*128 + n]                      */
__global__ void k_conv1(const uint16_t* __restrict__ xd,
                        const uint16_t* __restrict__ w1p,
                        uint16_t* __restrict__ f) {
  __shared__ short8 As[512];
  __shared__ short8 Bs[512];
  int bid = blockIdx.x;
  int w = 0;
  while (w < NW - 1 && bid >= W_TEND[w]) w++;
  int rel = bid - W_TSTART[w];
  int tpb = W_TPB[w];
  int b  = rel / tpb;
  int mt = rel - b * tpb;
  int m0 = mt << 7;
  int sh = W_SH[w], sw = W_SW[w];
  int fh = sh - 6, fw = sw - 6;
  int fhfw = fh * fw;
  float invfw = W_INVFW[w];
  int xdo = W_XDOFF[w];
  int fo  = W_FOFF[w];
  int tid = threadIdx.x;
  int lane = tid & 63, wv = tid >> 6;
  int mn = tid & 127, q0 = tid >> 7;

  int pm0 = m0 + mn; if (pm0 > fhfw - 1) pm0 = fhfw - 1;
  int fy0 = (int)(((float)pm0 + 0.5f) * invfw);
  int fx0 = pm0 - fy0 * fw;
  const uint16_t* arow = xd + xdo + (b * 3) * sh * sw;
  const uint16_t* brow = w1p + mn * 192;

  f32x4 acc[4][4];
  #pragma unroll
  for (int i = 0; i < 4; i++)
    #pragma unroll
    for (int j = 0; j < 4; j++)
      acc[i][j] = (f32x4){0.f, 0.f, 0.f, 0.f};

  for (int kk = 0; kk < 6; kk++) {
    short8 av[2], bv[2];
    #pragma unroll
    for (int j = 0; j < 2; j++) {
      int q = (j << 1) | q0;
      int gc = (kk << 2) + q;
      const uint16_t* src;
      if (gc < 21) {
        int ch = gc / 7, ky = gc - ch * 7;
        src = arow + (ch * sh + fy0 + ky) * sw + fx0;
      } else {
        src = xd;  /* dummy; matching weights are zero */
      }
      short8 pk;
      pk[0]=(short)src[0]; pk[1]=(short)src[1]; pk[2]=(short)src[2]; pk[3]=(short)src[3];
      pk[4]=(short)src[4]; pk[5]=(short)src[5]; pk[6]=(short)src[6]; pk[7]=(short)src[7];
      av[j] = pk;
      bv[j] = *(const short8*)(brow + (kk << 5) + (q << 3));
    }
    __syncthreads();
    #pragma unroll
    for (int j = 0; j < 2; j++) {
      int ck = (j << 8) + tid;
      As[ck] = av[j];
      Bs[ck] = bv[j];
    }
    __syncthreads();
    int q = lane >> 4, ln = lane & 15;
    int wmB = (wv >> 1) << 6, wnB = (wv & 1) << 6;
    short8 af[4], bfr[4];
    #pragma unroll
    for (int i = 0; i < 4; i++) af[i]  = As[(q << 7) + wmB + (i << 4) + ln];
    #pragma unroll
    for (int j = 0; j < 4; j++) bfr[j] = Bs[(q << 7) + wnB + (j << 4) + ln];
    #pragma unroll
    for (int i = 0; i < 4; i++)
      #pragma unroll
      for (int j = 0; j < 4; j++)
        acc[i][j] = __builtin_amdgcn_mfma_f32_16x16x32_bf16(af[i], bfr[j], acc[i][j], 0, 0, 0);
  }

  int q = lane >> 4, ln = lane & 15;
  int wmB = (wv >> 1) << 6, wnB = (wv & 1) << 6;
  int base = fo + b * fhfw * 128;
  #pragma unroll
  for (int i = 0; i < 4; i++) {
    #pragma unroll
    for (int j = 0; j < 4; j++) {
      int n = wnB + (j << 4) + ln;
      int mrow = m0 + wmB + (i << 4) + (q << 2);
      #pragma unroll
      for (int r = 0; r < 4; r++) {
        int pm = mrow + r;
        if (pm < fhfw) f[base + pm * 128 + n] = f2bf(acc[i][j][r]);
      }
    }
  }
}

/* ---------------- BN1 stats over the virtual mosaic via multiplicities ----
   NHWC f: block = (w, b), 1024 threads: c = tid&127, e strided by 8        */
__global__ void k_stats1(const uint16_t* __restrict__ f, float* __restrict__ sums) {
  __shared__ float cwt[960];
  __shared__ float sS[128], sQ[128];
  int w = blockIdx.x;
  int b = blockIdx.y;
  int sh = W_SH[w], sw = W_SW[w];
  int fh = sh - 6, fw = sw - 6, fhfw = fh * fw;
  int h = W_H[w], ww = W_WW[w];
  int tid = threadIdx.x;
  if (tid < 128) { sS[tid] = 0.f; sQ[tid] = 0.f; }
  for (int e = tid; e < fhfw; e += 1024) {
    int fy = e / fw, fx = e - fy * fw;
    int cy = ((fy + 1) * h + fh - 1) / fh - (fy * h + fh - 1) / fh;
    int cx = ((fx + 1) * ww + fw - 1) / fw - (fx * ww + fw - 1) / fw;
    cwt[e] = (float)(cy * cx);
  }
  __syncthreads();
  int c = tid & 127, eh = tid >> 7;
  int base = W_FOFF[w] + b * fhfw * 128;
  float s = 0.f, q2 = 0.f;
  for (int e = eh; e < fhfw; e += 8) {
    float v = bf2f(f[base + e * 128 + c]);
    float cw = cwt[e];
    s += v * cw; q2 += v * v * cw;
  }
  atomicAdd(&sS[c], s);
  atomicAdd(&sQ[c], q2);
  __syncthreads();
  if (tid < 128) {
    atomicAdd(&sums[tid], sS[tid]);
    atomicAdd(&sums[128 + tid], sQ[tid]);
  }
}

__global__ void k_bnparam(const float* __restrict__ sums,
                          const float* __restrict__ gamma, const float* __restrict__ beta,
                          float n, float* __restrict__ scale, float* __restrict__ bias) {
  int c = threadIdx.x;
  float mean = sums[c] / n;
  float var = sums[128 + c] / n - mean * mean;
  var = fmaxf(var, 0.f);
  float sc = gamma[c] / sqrtf(var + 1e-5f);
  scale[c] = sc;
  bias[c] = beta[c] - mean * sc;
}

/* ---------------- BN1+ReLU+maxpool gather into padded NHWC bf16 -----------
   thread = 8 channels of one pooled pixel; 16 threads/pixel, 16 px/block    */
__global__ void k_maxpool(const uint16_t* __restrict__ f,
                          const float* __restrict__ scale, const float* __restrict__ bias,
                          const int2* __restrict__ tab,
                          uint16_t* __restrict__ pooled) {
  int tid = threadIdx.x;
  int g = blockIdx.x * 16 + (tid >> 4);   /* pooled pixel in [0, 16*114*114) */
  int c0 = (tid & 15) << 3;
  int xx = g % 114;
  int r  = g / 114;
  int yy = r % 114;
  int bb = r / 114;
  short8 outv = (short8){0,0,0,0,0,0,0,0};
  if (yy >= 1 && yy <= 112 && xx >= 1 && xx <= 112) {
    float m[8];
    #pragma unroll
    for (int k = 0; k < 8; k++) m[k] = -1e30f;
    int py = yy - 1, px = xx - 1;
    #pragma unroll
    for (int dy = 0; dy < 3; dy++) {
      int y = 2 * py - 1 + dy;
      if (y < 0) continue;
      #pragma unroll
      for (int dx = 0; dx < 3; dx++) {
        int x = 2 * px - 1 + dx;
        if (x < 0) continue;
        int2 t = tab[y * IMG + x];
        short8 v = *(const short8*)(f + t.x + bb * t.y + c0);
        #pragma unroll
        for (int k = 0; k < 8; k++) m[k] = fmaxf(m[k], bf2f((uint16_t)v[k]));
      }
    }
    f32x4 s0 = *(const f32x4*)(scale + c0);
    f32x4 s1 = *(const f32x4*)(scale + c0 + 4);
    f32x4 b0 = *(const f32x4*)(bias + c0);
    f32x4 b1 = *(const f32x4*)(bias + c0 + 4);
    #pragma unroll
    for (int k = 0; k < 4; k++) {
      outv[k]     = (short)f2bf(fmaxf(m[k]     * s0[k] + b0[k], 0.f));
      outv[k + 4] = (short)f2bf(fmaxf(m[k + 4] * s1[k] + b1[k], 0.f));
    }
  }
  *(short8*)(pooled + (size_t)g * 128 + c0) = outv;
}

/* ---------------- conv2 implicit GEMM: K=64 stages staged via
   global_load_lds (async, no VGPR round-trip) + fused BN2 stats ------------ */
__global__ void k_conv2(const uint16_t* __restrict__ pooled,
                        const uint16_t* __restrict__ w2t,
                        float* __restrict__ out, float* __restrict__ sums) {
  __shared__ short8 As[1024];
  __shared__ short8 Bs[1024];
  __shared__ float sS[128], sQ[128];
  int bid = blockIdx.x;
  int b = bid / 98;
  int m0 = bid << 7;
  int local0 = m0 - b * 12544;
  int tid = threadIdx.x;
  int lane = tid & 63, wv = tid >> 6;
  int mn = tid & 127, q0 = tid >> 7;
  int loc = local0 + mn;
  int yp = loc / 112;
  int xp = loc - yp * 112;
  /* per-lane global bases (include q0's 8-element offset) */
  const uint16_t* ap = pooled + (size_t)b * 114 * 114 * 128
                       + (yp * 114 + xp) * 128 + (q0 << 3);
  const uint16_t* brow = w2t + mn * 1152 + (q0 << 3);
  if (tid < 128) { sS[tid] = 0.f; sQ[tid] = 0.f; }

  f32x4 acc[4][4];
  #pragma unroll
  for (int i = 0; i < 4; i++)
    #pragma unroll
    for (int j = 0; j < 4; j++)
      acc[i][j] = (f32x4){0.f, 0.f, 0.f, 0.f};

  int q = lane >> 4, ln = lane & 15;
  int wmB = (wv >> 1) << 6, wnB = (wv & 1) << 6;

  for (int s = 0; s < 18; s++) {
    #pragma unroll
    for (int u = 0; u < 2; u++) {
      int kk = (s << 1) + u;
      int tap = kk >> 2;
      int c0 = (kk & 3) << 5;
      int ty = tap / 3, tx = tap - ty * 3;
      const uint16_t* ga = ap + ((ty * 114 + tx) << 7) + c0;
      const uint16_t* gb = brow + (kk << 5);
      #pragma unroll
      for (int j = 0; j < 2; j++) {
        int ck = (u << 9) + (j << 8) + tid;
        GLD16(ga + (j << 4), &As[ck]);
        GLD16(gb + (j << 4), &Bs[ck]);
      }
    }
    __syncthreads();
    #pragma unroll
    for (int u = 0; u < 2; u++) {
      short8 af[4], bfr[4];
      #pragma unroll
      for (int i = 0; i < 4; i++) af[i]  = As[(u << 9) + (q << 7) + wmB + (i << 4) + ln];
      #pragma unroll
      for (int j = 0; j < 4; j++) bfr[j] = Bs[(u << 9) + (q << 7) + wnB + (j << 4) + ln];
      #pragma unroll
      for (int i = 0; i < 4; i++)
        #pragma unroll
        for (int j = 0; j < 4; j++)
          acc[i][j] = __builtin_amdgcn_mfma_f32_16x16x32_bf16(af[i], bfr[j], acc[i][j], 0, 0, 0);
    }
    __syncthreads();
  }

  #pragma unroll
  for (int i = 0; i < 4; i++) {
    #pragma unroll
    for (int j = 0; j < 4; j++) {
      int n = wnB + (j << 4) + ln;
      int prow = local0 + wmB + (i << 4) + (q << 2);
      float* dst = out + (size_t)(b * 128 + n) * 12544 + prow;
      *(f32x4*)dst = acc[i][j];
    }
  }
  /* fused BN2 partial stats: per-channel sums over this block's 128 rows */
  #pragma unroll
  for (int j = 0; j < 4; j++) {
    int n = wnB + (j << 4) + ln;
    float s = 0.f, q2 = 0.f;
    #pragma unroll
    for (int i = 0; i < 4; i++)
      #pragma unroll
      for (int r = 0; r < 4; r++) {
        float v = acc[i][j][r];
        s += v; q2 += v * v;
      }
    atomicAdd(&sS[n], s);
    atomicAdd(&sQ[n], q2);
  }
  __syncthreads();
  if (tid < 128) {
    atomicAdd(&sums[tid], sS[tid]);
    atomicAdd(&sums[128 + tid], sQ[tid]);
  }
}

__global__ void k_final(f32x4* __restrict__ out,
                        const float* __restrict__ scale, const float* __restrict__ bias) {
  int i = blockIdx.x * 256 + threadIdx.x;
  int c = (i / 3136) & 127;   /* 12544 floats per channel = 3136 float4 */
  f32x4 v = out[i];
  float sc = scale[c], bi = bias[c];
  #pragma unroll
  for (int k = 0; k < 4; k++) v[k] = fmaxf(v[k] * sc + bi, 0.f);
  out[i] = v;
}

extern "C" void kernel_launch(void* const* d_in, const int* in_sizes, int n_in,
                              void* d_out, int out_size, void* d_ws, size_t ws_size,
                              hipStream_t stream) {
  (void)in_sizes; (void)n_in; (void)out_size; (void)ws_size;
  const float* inp = (const float*)d_in[0];
  const float* w1  = (const float*)d_in[1];
  const float* g1  = (const float*)d_in[2];
  const float* b1  = (const float*)d_in[3];
  const float* w2  = (const float*)d_in[4];
  const float* g2  = (const float*)d_in[5];
  const float* b2  = (const float*)d_in[6];
  float* out = (float*)d_out;
  char* ws = (char*)d_ws;
  uint16_t* xd     = (uint16_t*)(ws + XD_OFF_B);
  uint16_t* pooled = (uint16_t*)(ws + POOL_OFF_B);
  uint16_t* w1p    = (uint16_t*)(ws + W1P_OFF_B);
  uint16_t* w2t    = (uint16_t*)(ws + W2T_OFF_B);
  float* stats  = (float*)(ws + STATS_OFF_B);
  int2*  tab    = (int2*)((char*)d_out + TAB_OUT_OFF_B);  /* d_out tail; dead before conv2 writes */
  float* sums1  = stats;
  float* sums2  = stats + 256;
  float* scale1 = stats + 512;
  float* bias1  = stats + 640;
  float* scale2 = stats + 768;
  float* bias2  = stats + 896;
  uint16_t* f = (uint16_t*)d_out;   /* bf16 scratch inside d_out; dead before conv2 writes */

  hipMemsetAsync(stats, 0, 2048, stream);
  k_prep   <<<dim3(672),        dim3(256),  0, stream>>>(w1, w2, w1p, w2t);
  k_tapoff <<<dim3(196),        dim3(256),  0, stream>>>(tab);
  k_resize <<<dim3(7119),       dim3(256),  0, stream>>>(inp, xd);
  k_conv1  <<<dim3(3072),       dim3(256),  0, stream>>>(xd, w1p, f);
  k_stats1 <<<dim3(28, 16),     dim3(1024), 0, stream>>>(f, sums1);
  k_bnparam<<<dim3(1),          dim3(128),  0, stream>>>(sums1, g1, b1, 802816.0f, scale1, bias1);
  k_maxpool<<<dim3(12996),      dim3(256),  0, stream>>>(f, scale1, bias1, tab, pooled);
  k_conv2  <<<dim3(1568),       dim3(256),  0, stream>>>(pooled, w2t, out, sums2);
  k_bnparam<<<dim3(1),          dim3(128),  0, stream>>>(sums2, g2, b2, 200704.0f, scale2, bias2);
  k_final  <<<dim3(25088),      dim3(256),  0, stream>>>((f32x4*)out, scale2, bias2);
}

// Round 7
// 414.856 us; speedup vs baseline: 1.1929x; 1.1369x over previous
//
#include <hip/hip_runtime.h>
#include <stdint.h>

#define NW 28
#define IMG 224
#define XD_TOTAL 1822272
#define POOL_ELEMS 26615808   /* 16*114*114*128 */
#define OUT_ELEMS 25690112    /* 16*128*112*112 */

/* workspace byte offsets (unchanged from round-1 passing layout) */
#define XD_OFF_B    0
#define POOL_OFF_B  3644928
#define W1P_OFF_B   56876544
#define W2T_OFF_B   56925696
#define STATS_OFF_B 57220608
/* tab lives in d_out tail: f ends at byte 93,667,328 of 102,760,448 */
#define TAB_OUT_OFF_B 93667328

typedef __attribute__((ext_vector_type(8))) short short8;
typedef __attribute__((ext_vector_type(4))) float f32x4;

/* async global->LDS 16B: per-lane global addr, LDS dest = uniform base + lane*16 */
#define GLD16(gp, lp) __builtin_amdgcn_global_load_lds( \
    (const __attribute__((address_space(1))) void*)(gp), \
    (__attribute__((address_space(3))) void*)(lp), 16, 0, 0)

/* w: t, l, h, w, sh, sw, xd_off, f_off, tile_start, tiles_per_b */
#define WIN_TABLE(W) \
  W(  0,  0, 16,208, 14,110,       0,        0,    0, 7) \
  W( 16,  0,208, 16,110, 14,   73920,  1703936,  112, 7) \
  W(208, 16, 16,208, 14,110,  147840,  3407872,  224, 7) \
  W(  0,208,208, 16,110, 14,  221760,  5111808,  336, 7) \
  W( 16, 16, 16,176, 15,102,  295680,  6815744,  448, 7) \
  W( 32, 16,176, 16,102, 15,  369120,  8585216,  560, 7) \
  W(192, 32, 16,176, 15,102,  442560, 10354688,  672, 7) \
  W( 16,192,176, 16,102, 15,  516000, 12124160,  784, 7) \
  W( 32, 32, 16,144, 16, 93,  589440, 13893632,  896, 7) \
  W( 48, 32,144, 16, 93, 16,  660864, 15675392, 1008, 7) \
  W(176, 48, 16,144, 16, 93,  732288, 17457152, 1120, 7) \
  W( 32,176,144, 16, 93, 16,  803712, 19238912, 1232, 7) \
  W( 48, 48, 16,112, 18, 82,  875136, 21020672, 1344, 8) \
  W( 64, 48,112, 16, 82, 18,  945984, 22888448, 1472, 8) \
  W(160, 64, 16,112, 18, 82, 1016832, 24756224, 1600, 8) \
  W( 48,160,112, 16, 82, 18, 1087680, 26624000, 1728, 8) \
  W( 64, 64, 16, 80, 21, 69, 1158528, 28491776, 1856, 8) \
  W( 80, 64, 80, 16, 69, 21, 1228080, 30427136, 1984, 8) \
  W(144, 80, 16, 80, 21, 69, 1297632, 32362496, 2112, 8) \
  W( 64,144, 80, 16, 69, 21, 1367184, 34297856, 2240, 8) \
  W( 80, 80, 16, 48, 24, 51, 1436736, 36233216, 2368, 7) \
  W( 96, 80, 48, 16, 51, 24, 1495488, 37892096, 2480, 7) \
  W(128, 96, 16, 48, 24, 51, 1554240, 39550976, 2592, 7) \
  W( 80,128, 48, 16, 51, 24, 1612992, 41209856, 2704, 7) \
  W( 96, 96, 16, 16, 28, 28, 1671744, 42868736, 2816, 4) \
  W(112, 96, 16, 16, 28, 28, 1709376, 43859968, 2880, 4) \
  W(112,112, 16, 16, 28, 28, 1747008, 44851200, 2944, 4) \
  W( 96,112, 16, 16, 28, 28, 1784640, 45842432, 3008, 4)

#define GT(t,l,h,ww,sh,sw,xdo,fo,ts,tpb) (t),
#define GL(t,l,h,ww,sh,sw,xdo,fo,ts,tpb) (l),
#define GH(t,l,h,ww,sh,sw,xdo,fo,ts,tpb) (h),
#define GW(t,l,h,ww,sh,sw,xdo,fo,ts,tpb) (ww),
#define GSH(t,l,h,ww,sh,sw,xdo,fo,ts,tpb) (sh),
#define GSW(t,l,h,ww,sh,sw,xdo,fo,ts,tpb) (sw),
#define GXO(t,l,h,ww,sh,sw,xdo,fo,ts,tpb) (xdo),
#define GFO(t,l,h,ww,sh,sw,xdo,fo,ts,tpb) (fo),
#define GTS(t,l,h,ww,sh,sw,xdo,fo,ts,tpb) (ts),
#define GTPB(t,l,h,ww,sh,sw,xdo,fo,ts,tpb) (tpb),
#define GXE(t,l,h,ww,sh,sw,xdo,fo,ts,tpb) ((xdo) + 48*(sh)*(sw)),
#define GTE(t,l,h,ww,sh,sw,xdo,fo,ts,tpb) ((ts) + 16*(tpb)),
#define GIH(t,l,h,ww,sh,sw,xdo,fo,ts,tpb) (1.0f/(float)(h)),
#define GIW(t,l,h,ww,sh,sw,xdo,fo,ts,tpb) (1.0f/(float)(ww)),
#define GIFW(t,l,h,ww,sh,sw,xdo,fo,ts,tpb) (1.0f/(float)((sw)-6)),
#define GRSY(t,l,h,ww,sh,sw,xdo,fo,ts,tpb) ((float)((h)+12)/(float)(sh)),
#define GRSX(t,l,h,ww,sh,sw,xdo,fo,ts,tpb) ((float)((ww)+12)/(float)(sw)),
#define GI3(t,l,h,ww,sh,sw,xdo,fo,ts,tpb) (1.0f/(float)(3*(sh)*(sw))),
#define GISS(t,l,h,ww,sh,sw,xdo,fo,ts,tpb) (1.0f/(float)((sh)*(sw))),
#define GISW(t,l,h,ww,sh,sw,xdo,fo,ts,tpb) (1.0f/(float)(sw)),

__constant__ int   W_T[NW]     = { WIN_TABLE(GT) };
__constant__ int   W_L[NW]     = { WIN_TABLE(GL) };
__constant__ int   W_H[NW]     = { WIN_TABLE(GH) };
__constant__ int   W_WW[NW]    = { WIN_TABLE(GW) };
__constant__ int   W_SH[NW]    = { WIN_TABLE(GSH) };
__constant__ int   W_SW[NW]    = { WIN_TABLE(GSW) };
__constant__ int   W_XDOFF[NW] = { WIN_TABLE(GXO) };
__constant__ int   W_FOFF[NW]  = { WIN_TABLE(GFO) };
__constant__ int   W_TSTART[NW]= { WIN_TABLE(GTS) };
__constant__ int   W_TPB[NW]   = { WIN_TABLE(GTPB) };
__constant__ int   W_XDEND[NW] = { WIN_TABLE(GXE) };
__constant__ int   W_TEND[NW]  = { WIN_TABLE(GTE) };
__constant__ float W_INVH[NW]  = { WIN_TABLE(GIH) };
__constant__ float W_INVW[NW]  = { WIN_TABLE(GIW) };
__constant__ float W_INVFW[NW] = { WIN_TABLE(GIFW) };
__constant__ float W_RSY[NW]   = { WIN_TABLE(GRSY) };
__constant__ float W_RSX[NW]   = { WIN_TABLE(GRSX) };
__constant__ float W_INV3[NW]  = { WIN_TABLE(GI3) };
__constant__ float W_INVSS[NW] = { WIN_TABLE(GISS) };
__constant__ float W_INVSW[NW] = { WIN_TABLE(GISW) };

__device__ __forceinline__ float bf2f(uint16_t h) {
  union { uint32_t u; float f; } v; v.u = ((uint32_t)h) << 16; return v.f;
}
__device__ __forceinline__ uint16_t f2bf(float x) {
  union { float f; uint32_t u; } v; v.f = x;
  uint32_t r = v.u + 0x7FFFu + ((v.u >> 16) & 1u);
  return (uint16_t)(r >> 16);
}

/* ---------------- prep: pack conv weights to bf16 ------------------------
   w1p: [cout][192] GEMM-B^T rows (k = (ch*7+ky)*8 + kx)
   w2s: conv2 LDS image, XOR-swizzled:
        elem ((tap*128 + n)*16 + cc)*8 + e  =  w2[n][ci][ty][tx]
        with ci = ((cc ^ (n&15))<<3) + e, ty=tap/3, tx=tap%3                */
__global__ void k_prep(const float* __restrict__ w1, const float* __restrict__ w2,
                       uint16_t* __restrict__ w1p, uint16_t* __restrict__ w2s) {
  int i = blockIdx.x * 256 + threadIdx.x;
  if (i < 128 * 192) {
    int cout = i / 192, k = i - cout * 192;
    int chunk = k >> 3, kx = k & 7;
    float v = 0.f;
    if (chunk < 21 && kx < 7) {
      int ch = chunk / 7, ky = chunk - ch * 7;
      v = w1[((cout * 3 + ch) * 7 + ky) * 7 + kx];
    }
    w1p[i] = f2bf(v);
  }
  int j2 = i - 128 * 192;
  if (j2 >= 0 && j2 < 147456) {
    int e   = j2 & 7;
    int cc  = (j2 >> 3) & 15;
    int n   = (j2 >> 7) & 127;
    int tap = j2 >> 14;
    int ci  = ((cc ^ (n & 15)) << 3) + e;
    int ty = tap / 3, tx = tap - ty * 3;
    w2s[j2] = f2bf(w2[((n * 128 + ci) * 3 + ty) * 3 + tx]);
  }
}

/* ---------------- per-(y,x) tap lookup table for maxpool gather ----------- */
__global__ void k_tapoff(int2* __restrict__ tab) {
  int i = blockIdx.x * 256 + threadIdx.x;
  if (i >= IMG * IMG) return;
  int y = i / IMG, x = i - y * IMG;
  int dmin = min(min(y, 223 - y), min(x, 223 - x));
  int s = dmin >> 4; if (s > 6) s = 6;
  int b2 = (s << 4) + 16, cc = 208 - (s << 4);
  int side;
  if (y < b2) side = (x < cc) ? 0 : 3;
  else if (y >= cc) side = (x >= b2) ? 2 : 1;
  else side = (x < b2) ? 1 : 3;
  int w = (s << 2) + side;
  int fh = W_SH[w] - 6, fw = W_SW[w] - 6;
  int fy = (int)(((float)((y - W_T[w]) * fh) + 0.5f) * W_INVH[w]);
  int fx = (int)(((float)((x - W_L[w]) * fw) + 0.5f) * W_INVW[w]);
  tab[i] = make_int2(W_FOFF[w] + (fy * fw + fx) * 128, fh * fw * 128);
}

/* ---------------- resize: antialiased linear, per output element ---------- */
__global__ void k_resize(const float* __restrict__ inp, uint16_t* __restrict__ xd) {
  int idx = blockIdx.x * 256 + threadIdx.x;
  if (idx >= XD_TOTAL) return;
  int w = 0;
  while (w < NW - 1 && idx >= W_XDEND[w]) w++;
  int rem = idx - W_XDOFF[w];
  int sh = W_SH[w], sw = W_SW[w];
  int shsw = sh * sw;
  int b  = (int)(((float)rem + 0.5f) * W_INV3[w]);
  int r2 = rem - b * 3 * shsw;
  int ch = (int)(((float)r2 + 0.5f) * W_INVSS[w]);
  int r3 = r2 - ch * shsw;
  int oy = (int)(((float)r3 + 0.5f) * W_INVSW[w]);
  int ox = r3 - oy * sw;
  int t = W_T[w], l = W_L[w], h = W_H[w], ww = W_WW[w];
  int hiny = h + 12, hinx = ww + 12;
  float rsy = W_RSY[w], rsx = W_RSX[w];
  float iky = 1.0f / rsy, ikx = 1.0f / rsx;
  float sfy = ((float)oy + 0.5f) * rsy - 0.5f;
  float sfx = ((float)ox + 0.5f) * rsx - 0.5f;
  int y0 = (int)ceilf(sfy - rsy); if (y0 < 0) y0 = 0;
  int y1 = (int)floorf(sfy + rsy); if (y1 > hiny - 1) y1 = hiny - 1;
  int x0 = (int)ceilf(sfx - rsx); if (x0 < 0) x0 = 0;
  int x1 = (int)floorf(sfx + rsx); if (x1 > hinx - 1) x1 = hinx - 1;
  float wy[4], wx[4], sy = 0.f, sx = 0.f;
  #pragma unroll
  for (int k = 0; k < 4; k++) {
    int iy = y0 + k;
    float a = (iy <= y1) ? fmaxf(0.f, 1.f - fabsf((float)iy - sfy) * iky) : 0.f;
    wy[k] = a; sy += a;
    int ix = x0 + k;
    float a2 = (ix <= x1) ? fmaxf(0.f, 1.f - fabsf((float)ix - sfx) * ikx) : 0.f;
    wx[k] = a2; sx += a2;
  }
  const float* src = inp + (b * 3 + ch) * IMG * IMG;
  float accv = 0.f;
  #pragma unroll
  for (int ky = 0; ky < 4; ky++) {
    int gy = t + y0 + ky - 6;
    if (wy[ky] > 0.f && gy >= 0 && gy < IMG) {
      float rowa = 0.f;
      #pragma unroll
      for (int kx = 0; kx < 4; kx++) {
        int gx = l + x0 + kx - 6;
        if (wx[kx] > 0.f && gx >= 0 && gx < IMG)
          rowa += wx[kx] * src[gy * IMG + gx];
      }
      accv += wy[ky] * rowa;
    }
  }
  xd[idx] = f2bf(accv / (sy * sx));
}

/* ---------------- conv1 as implicit GEMM: M=window pixels, K=192, N=128 ---
   f output layout: NHWC  f[fo + (b*fhfw + pm)*128 + n]                      */
__global__ void k_conv1(const uint16_t* __restrict__ xd,
                        const uint16_t* __restrict__ w1p,
                        uint16_t* __restrict__ f) {
  __shared__ short8 As[512];
  __shared__ short8 Bs[512];
  int bid = blockIdx.x;
  int w = 0;
  while (w < NW - 1 && bid >= W_TEND[w]) w++;
  int rel = bid - W_TSTART[w];
  int tpb = W_TPB[w];
  int b  = rel / tpb;
  int mt = rel - b * tpb;
  int m0 = mt << 7;
  int sh = W_SH[w], sw = W_SW[w];
  int fh = sh - 6, fw = sw - 6;
  int fhfw = fh * fw;
  float invfw = W_INVFW[w];
  int xdo = W_XDOFF[w];
  int fo  = W_FOFF[w];
  int tid = threadIdx.x;
  int lane = tid & 63, wv = tid >> 6;
  int mn = tid & 127, q0 = tid >> 7;

  int pm0 = m0 + mn; if (pm0 > fhfw - 1) pm0 = fhfw - 1;
  int fy0 = (int)(((float)pm0 + 0.5f) * invfw);
  int fx0 = pm0 - fy0 * fw;
  const uint16_t* arow = xd + xdo + (b * 3) * sh * sw;
  const uint16_t* brow = w1p + mn * 192;

  f32x4 acc[4][4];
  #pragma unroll
  for (int i = 0; i < 4; i++)
    #pragma unroll
    for (int j = 0; j < 4; j++)
      acc[i][j] = (f32x4){0.f, 0.f, 0.f, 0.f};

  for (int kk = 0; kk < 6; kk++) {
    short8 av[2], bv[2];
    #pragma unroll
    for (int j = 0; j < 2; j++) {
      int q = (j << 1) | q0;
      int gc = (kk << 2) + q;
      const uint16_t* src;
      if (gc < 21) {
        int ch = gc / 7, ky = gc - ch * 7;
        src = arow + (ch * sh + fy0 + ky) * sw + fx0;
      } else {
        src = xd;  /* dummy; matching weights are zero */
      }
      short8 pk;
      pk[0]=(short)src[0]; pk[1]=(short)src[1]; pk[2]=(short)src[2]; pk[3]=(short)src[3];
      pk[4]=(short)src[4]; pk[5]=(short)src[5]; pk[6]=(short)src[6]; pk[7]=(short)src[7];
      av[j] = pk;
      bv[j] = *(const short8*)(brow + (kk << 5) + (q << 3));
    }
    __syncthreads();
    #pragma unroll
    for (int j = 0; j < 2; j++) {
      int ck = (j << 8) + tid;
      As[ck] = av[j];
      Bs[ck] = bv[j];
    }
    __syncthreads();
    int q = lane >> 4, ln = lane & 15;
    int wmB = (wv >> 1) << 6, wnB = (wv & 1) << 6;
    short8 af[4], bfr[4];
    #pragma unroll
    for (int i = 0; i < 4; i++) af[i]  = As[(q << 7) + wmB + (i << 4) + ln];
    #pragma unroll
    for (int j = 0; j < 4; j++) bfr[j] = Bs[(q << 7) + wnB + (j << 4) + ln];
    #pragma unroll
    for (int i = 0; i < 4; i++)
      #pragma unroll
      for (int j = 0; j < 4; j++)
        acc[i][j] = __builtin_amdgcn_mfma_f32_16x16x32_bf16(af[i], bfr[j], acc[i][j], 0, 0, 0);
  }

  int q = lane >> 4, ln = lane & 15;
  int wmB = (wv >> 1) << 6, wnB = (wv & 1) << 6;
  int base = fo + b * fhfw * 128;
  #pragma unroll
  for (int i = 0; i < 4; i++) {
    #pragma unroll
    for (int j = 0; j < 4; j++) {
      int n = wnB + (j << 4) + ln;
      int mrow = m0 + wmB + (i << 4) + (q << 2);
      #pragma unroll
      for (int r = 0; r < 4; r++) {
        int pm = mrow + r;
        if (pm < fhfw) f[base + pm * 128 + n] = f2bf(acc[i][j][r]);
      }
    }
  }
}

/* ---------------- BN1 stats over the virtual mosaic via multiplicities ----
   NHWC f: block = (w, b), 1024 threads: c = tid&127, e strided by 8        */
__global__ void k_stats1(const uint16_t* __restrict__ f, float* __restrict__ sums) {
  __shared__ float cwt[960];
  __shared__ float sS[128], sQ[128];
  int w = blockIdx.x;
  int b = blockIdx.y;
  int sh = W_SH[w], sw = W_SW[w];
  int fh = sh - 6, fw = sw - 6, fhfw = fh * fw;
  int h = W_H[w], ww = W_WW[w];
  int tid = threadIdx.x;
  if (tid < 128) { sS[tid] = 0.f; sQ[tid] = 0.f; }
  for (int e = tid; e < fhfw; e += 1024) {
    int fy = e / fw, fx = e - fy * fw;
    int cy = ((fy + 1) * h + fh - 1) / fh - (fy * h + fh - 1) / fh;
    int cx = ((fx + 1) * ww + fw - 1) / fw - (fx * ww + fw - 1) / fw;
    cwt[e] = (float)(cy * cx);
  }
  __syncthreads();
  int c = tid & 127, eh = tid >> 7;
  int base = W_FOFF[w] + b * fhfw * 128;
  float s = 0.f, q2 = 0.f;
  for (int e = eh; e < fhfw; e += 8) {
    float v = bf2f(f[base + e * 128 + c]);
    float cw = cwt[e];
    s += v * cw; q2 += v * v * cw;
  }
  atomicAdd(&sS[c], s);
  atomicAdd(&sQ[c], q2);
  __syncthreads();
  if (tid < 128) {
    atomicAdd(&sums[tid], sS[tid]);
    atomicAdd(&sums[128 + tid], sQ[tid]);
  }
}

__global__ void k_bnparam(const float* __restrict__ sums,
                          const float* __restrict__ gamma, const float* __restrict__ beta,
                          float n, float* __restrict__ scale, float* __restrict__ bias) {
  int c = threadIdx.x;
  float mean = sums[c] / n;
  float var = sums[128 + c] / n - mean * mean;
  var = fmaxf(var, 0.f);
  float sc = gamma[c] / sqrtf(var + 1e-5f);
  scale[c] = sc;
  bias[c] = beta[c] - mean * sc;
}

/* ---------------- BN1+ReLU+maxpool gather into padded NHWC bf16 -----------
   thread = 8 channels of one pooled pixel; 16 threads/pixel, 16 px/block    */
__global__ void k_maxpool(const uint16_t* __restrict__ f,
                          const float* __restrict__ scale, const float* __restrict__ bias,
                          const int2* __restrict__ tab,
                          uint16_t* __restrict__ pooled) {
  int tid = threadIdx.x;
  int g = blockIdx.x * 16 + (tid >> 4);   /* pooled pixel in [0, 16*114*114) */
  int c0 = (tid & 15) << 3;
  int xx = g % 114;
  int r  = g / 114;
  int yy = r % 114;
  int bb = r / 114;
  short8 outv = (short8){0,0,0,0,0,0,0,0};
  if (yy >= 1 && yy <= 112 && xx >= 1 && xx <= 112) {
    float m[8];
    #pragma unroll
    for (int k = 0; k < 8; k++) m[k] = -1e30f;
    int py = yy - 1, px = xx - 1;
    #pragma unroll
    for (int dy = 0; dy < 3; dy++) {
      int y = 2 * py - 1 + dy;
      if (y < 0) continue;
      #pragma unroll
      for (int dx = 0; dx < 3; dx++) {
        int x = 2 * px - 1 + dx;
        if (x < 0) continue;
        int2 t = tab[y * IMG + x];
        short8 v = *(const short8*)(f + t.x + bb * t.y + c0);
        #pragma unroll
        for (int k = 0; k < 8; k++) m[k] = fmaxf(m[k], bf2f((uint16_t)v[k]));
      }
    }
    f32x4 s0 = *(const f32x4*)(scale + c0);
    f32x4 s1 = *(const f32x4*)(scale + c0 + 4);
    f32x4 b0 = *(const f32x4*)(bias + c0);
    f32x4 b1 = *(const f32x4*)(bias + c0 + 4);
    #pragma unroll
    for (int k = 0; k < 4; k++) {
      outv[k]     = (short)f2bf(fmaxf(m[k]     * s0[k] + b0[k], 0.f));
      outv[k + 4] = (short)f2bf(fmaxf(m[k + 4] * s1[k] + b1[k], 0.f));
    }
  }
  *(short8*)(pooled + (size_t)g * 128 + c0) = outv;
}

/* ---------------- conv2: 9 tap-stages x K=128, lane-contiguous staging ----
   LDS images (XOR-swizzled): As slot = pix*16 + (chunk ^ (pix&15)),
   Bs slot = n*16 + (chunk ^ (n&15)) (swizzle baked into w2s).
   Staging: 16 lanes cover one 256B pixel/cout row -> 16 lines per GLD.
   Frag read: slot = p*16 + (cq ^ ln) -> balanced banks.                      */
__global__ __launch_bounds__(256) void k_conv2(
                        const uint16_t* __restrict__ pooled,
                        const uint16_t* __restrict__ w2s,
                        float* __restrict__ out, float* __restrict__ sums) {
  __shared__ short8 As[2048];   /* 32 KB */
  __shared__ short8 Bs[2048];   /* 32 KB */
  int bid = blockIdx.x;
  int b = bid / 98;
  int m0 = bid << 7;
  int local0 = m0 - b * 12544;
  int tid = threadIdx.x;
  int lane = tid & 63, wv = tid >> 6;
  int q = lane >> 4, ln = lane & 15;
  int wmB = (wv >> 1) << 6, wnB = (wv & 1) << 6;
  const char* apc = (const char*)(pooled + (size_t)b * 114 * 114 * 128);

  /* staging geometry: thread covers slots wv*512 + r*64 + lane, r=0..7 */
  int slot0 = (wv << 9) + lane;
  int rowbyte[8];
  #pragma unroll
  for (int r = 0; r < 8; r++) {
    int slot = slot0 + (r << 6);
    int pix = slot >> 4;           /* 0..127 */
    int cc = slot & 15;            /* = lane&15 */
    int loc = local0 + pix;
    int yp = loc / 112, xp = loc - yp * 112;
    rowbyte[r] = ((yp * 114 + xp) << 8) + ((cc ^ (pix & 15)) << 4);
  }

  f32x4 acc[4][4];
  #pragma unroll
  for (int i = 0; i < 4; i++)
    #pragma unroll
    for (int j = 0; j < 4; j++)
      acc[i][j] = (f32x4){0.f, 0.f, 0.f, 0.f};

  #pragma unroll
  for (int tap = 0; tap < 9; tap++) {
    const int ty = tap / 3, tx = tap - ty * 3;
    const int tapoff = (ty * 114 + tx) << 8;
    const uint16_t* gb = w2s + (tap << 14) + (slot0 << 3);
    #pragma unroll
    for (int r = 0; r < 8; r++) {
      int slot = slot0 + (r << 6);
      GLD16(apc + tapoff + rowbyte[r], &As[slot]);
      GLD16(gb + (r << 9), &Bs[slot]);
    }
    __syncthreads();
    #pragma unroll
    for (int kk2 = 0; kk2 < 4; kk2++) {
      int cq = (kk2 << 2) + q;
      short8 af[4], bfr[4];
      #pragma unroll
      for (int i = 0; i < 4; i++)
        af[i] = As[((wmB + (i << 4) + ln) << 4) + (cq ^ ln)];
      #pragma unroll
      for (int j = 0; j < 4; j++)
        bfr[j] = Bs[((wnB + (j << 4) + ln) << 4) + (cq ^ ln)];
      #pragma unroll
      for (int i = 0; i < 4; i++)
        #pragma unroll
        for (int j = 0; j < 4; j++)
          acc[i][j] = __builtin_amdgcn_mfma_f32_16x16x32_bf16(af[i], bfr[j], acc[i][j], 0, 0, 0);
    }
    __syncthreads();
  }

  /* C-write */
  #pragma unroll
  for (int i = 0; i < 4; i++) {
    #pragma unroll
    for (int j = 0; j < 4; j++) {
      int n = wnB + (j << 4) + ln;
      int prow = local0 + wmB + (i << 4) + (q << 2);
      float* dst = out + (size_t)(b * 128 + n) * 12544 + prow;
      *(f32x4*)dst = acc[i][j];
    }
  }
  /* fused BN2 partial stats — reuse As as float scratch (A dead now) */
  float* sS = (float*)&As[0];
  float* sQ = sS + 128;
  if (tid < 128) { sS[tid] = 0.f; sQ[tid] = 0.f; }
  __syncthreads();
  #pragma unroll
  for (int j = 0; j < 4; j++) {
    int n = wnB + (j << 4) + ln;
    float s = 0.f, q2 = 0.f;
    #pragma unroll
    for (int i = 0; i < 4; i++)
      #pragma unroll
      for (int r = 0; r < 4; r++) {
        float v = acc[i][j][r];
        s += v; q2 += v * v;
      }
    atomicAdd(&sS[n], s);
    atomicAdd(&sQ[n], q2);
  }
  __syncthreads();
  if (tid < 128) {
    atomicAdd(&sums[tid], sS[tid]);
    atomicAdd(&sums[128 + tid], sQ[tid]);
  }
}

__global__ void k_final(f32x4* __restrict__ out,
                        const float* __restrict__ scale, const float* __restrict__ bias) {
  int i = blockIdx.x * 256 + threadIdx.x;
  int c = (i / 3136) & 127;   /* 12544 floats per channel = 3136 float4 */
  f32x4 v = out[i];
  float sc = scale[c], bi = bias[c];
  #pragma unroll
  for (int k = 0; k < 4; k++) v[k] = fmaxf(v[k] * sc + bi, 0.f);
  out[i] = v;
}

extern "C" void kernel_launch(void* const* d_in, const int* in_sizes, int n_in,
                              void* d_out, int out_size, void* d_ws, size_t ws_size,
                              hipStream_t stream) {
  (void)in_sizes; (void)n_in; (void)out_size; (void)ws_size;
  const float* inp = (const float*)d_in[0];
  const float* w1  = (const float*)d_in[1];
  const float* g1  = (const float*)d_in[2];
  const float* b1  = (const float*)d_in[3];
  const float* w2  = (const float*)d_in[4];
  const float* g2  = (const float*)d_in[5];
  const float* b2  = (const float*)d_in[6];
  float* out = (float*)d_out;
  char* ws = (char*)d_ws;
  uint16_t* xd     = (uint16_t*)(ws + XD_OFF_B);
  uint16_t* pooled = (uint16_t*)(ws + POOL_OFF_B);
  uint16_t* w1p    = (uint16_t*)(ws + W1P_OFF_B);
  uint16_t* w2s    = (uint16_t*)(ws + W2T_OFF_B);
  float* stats  = (float*)(ws + STATS_OFF_B);
  int2*  tab    = (int2*)((char*)d_out + TAB_OUT_OFF_B);  /* d_out tail; dead before conv2 writes */
  float* sums1  = stats;
  float* sums2  = stats + 256;
  float* scale1 = stats + 512;
  float* bias1  = stats + 640;
  float* scale2 = stats + 768;
  float* bias2  = stats + 896;
  uint16_t* f = (uint16_t*)d_out;   /* bf16 scratch inside d_out; dead before conv2 writes */

  hipMemsetAsync(stats, 0, 2048, stream);
  k_prep   <<<dim3(672),        dim3(256),  0, stream>>>(w1, w2, w1p, w2s);
  k_tapoff <<<dim3(196),        dim3(256),  0, stream>>>(tab);
  k_resize <<<dim3(7119),       dim3(256),  0, stream>>>(inp, xd);
  k_conv1  <<<dim3(3072),       dim3(256),  0, stream>>>(xd, w1p, f);
  k_stats1 <<<dim3(28, 16),     dim3(1024), 0, stream>>>(f, sums1);
  k_bnparam<<<dim3(1),          dim3(128),  0, stream>>>(sums1, g1, b1, 802816.0f, scale1, bias1);
  k_maxpool<<<dim3(12996),      dim3(256),  0, stream>>>(f, scale1, bias1, tab, pooled);
  k_conv2  <<<dim3(1568),       dim3(256),  0, stream>>>(pooled, w2s, out, sums2);
  k_bnparam<<<dim3(1),          dim3(128),  0, stream>>>(sums2, g2, b2, 200704.0f, scale2, bias2);
  k_final  <<<dim3(25088),      dim3(256),  0, stream>>>((f32x4*)out, scale2, bias2);
}